// Round 1
// baseline (2854.442 us; speedup 1.0000x reference)
//
#include <hip/hip_runtime.h>
#include <stdint.h>

// Problem constants
#define T_SEQ 128
#define B_SZ  32
#define H_DIM 1024
#define E_DIM 512
#define V_DIM 32000
#define SOS_TOK 1

typedef float v4f __attribute__((ext_vector_type(4)));
typedef short short8 __attribute__((ext_vector_type(8)));

// RNE float->bf16 (manual, no hip_bf16 API dependence)
__device__ inline uint16_t f2bf(float x) {
    uint32_t u = __float_as_uint(x);
    uint32_t r = (u + 0x7fffu + ((u >> 16) & 1u)) >> 16;
    return (uint16_t)r;
}
__device__ inline uint32_t pack2(float a, float b) {
    return (uint32_t)f2bf(a) | ((uint32_t)f2bf(b) << 16);
}

// ---------------------------------------------------------------------------
// Kernel T: transpose W_hh (H x H) -> Wt[k][n] = W_hh[n][k]
// ---------------------------------------------------------------------------
__global__ __launch_bounds__(256) void ktrans(const float* __restrict__ W,
                                              float* __restrict__ Wt) {
    __shared__ float tile[32][33];
    int bx = blockIdx.x, by = blockIdx.y;   // bx: k-tile, by: n-tile
    int c = threadIdx.x & 31, r0 = threadIdx.x >> 5;
#pragma unroll
    for (int l = 0; l < 4; ++l) {
        int r = r0 + l * 8;
        tile[r][c] = W[(by * 32 + r) * H_DIM + bx * 32 + c];
    }
    __syncthreads();
#pragma unroll
    for (int l = 0; l < 4; ++l) {
        int r = r0 + l * 8;
        Wt[(bx * 32 + r) * H_DIM + by * 32 + c] = tile[c][r];
    }
}

// ---------------------------------------------------------------------------
// Kernel E: xW[b,t,n] = emb[tok(b,t)] . W_ih[n,:] + b_ih[n] + b_hh[n]
// fp32 GEMM  M=4096 (b*T+t), N=1024, K=512.  64x64 tile, 4x4/thread.
// ---------------------------------------------------------------------------
__global__ __launch_bounds__(256) void kxw(const int* __restrict__ target,
                                           const float* __restrict__ emb,
                                           const float* __restrict__ Wih,
                                           const float* __restrict__ bih,
                                           const float* __restrict__ bhh,
                                           float* __restrict__ xW) {
    __shared__ float As[64][17];   // pad 17: conflict-free-ish reads
    __shared__ float Bs[64][17];
    __shared__ int   toks[64];
    int m0 = blockIdx.x * 64, n0 = blockIdx.y * 64;
    int tid = threadIdx.x;
    if (tid < 64) {
        int row = m0 + tid;                  // row = b*T + t
        int t = row & (T_SEQ - 1);
        toks[tid] = (t == 0) ? SOS_TOK : target[row];
    }
    __syncthreads();

    float acc[4][4] = {};
    int tx = tid & 15, ty = tid >> 4;
    int lr = tid >> 2, lc = (tid & 3) * 4;

    for (int k0 = 0; k0 < E_DIM; k0 += 16) {
        float4 av = *(const float4*)&emb[toks[lr] * E_DIM + k0 + lc];
        float4 bv = *(const float4*)&Wih[(n0 + lr) * E_DIM + k0 + lc];
        As[lr][lc + 0] = av.x; As[lr][lc + 1] = av.y;
        As[lr][lc + 2] = av.z; As[lr][lc + 3] = av.w;
        Bs[lr][lc + 0] = bv.x; Bs[lr][lc + 1] = bv.y;
        Bs[lr][lc + 2] = bv.z; Bs[lr][lc + 3] = bv.w;
        __syncthreads();
#pragma unroll
        for (int k = 0; k < 16; ++k) {
            float a[4], b[4];
#pragma unroll
            for (int j = 0; j < 4; ++j) { a[j] = As[ty * 4 + j][k]; b[j] = Bs[tx * 4 + j][k]; }
#pragma unroll
            for (int i = 0; i < 4; ++i)
#pragma unroll
                for (int j = 0; j < 4; ++j) acc[i][j] += a[i] * b[j];
        }
        __syncthreads();
    }
#pragma unroll
    for (int i = 0; i < 4; ++i) {
        int m = m0 + ty * 4 + i;
#pragma unroll
        for (int j = 0; j < 4; ++j) {
            int n = n0 + tx * 4 + j;
            xW[m * H_DIM + n] = acc[i][j] + bih[n] + bhh[n];
        }
    }
}

// ---------------------------------------------------------------------------
// Kernel S (x128): h_t = tanh(xW_t + h_{t-1} Wt), also store bf16 copy of h_t.
// grid 128 blocks x 1024 thr.  block j: b-group (j/32)*8, n-group (j%32)*32.
// k split 4-ways across tid>>8, LDS reduce.
// ---------------------------------------------------------------------------
__global__ __launch_bounds__(1024) void kstep(const float* __restrict__ hprev,
                                              const float* __restrict__ Wt,
                                              const float* __restrict__ xW,
                                              float* __restrict__ hnext,
                                              uint16_t* __restrict__ Hb,
                                              int t) {
    __shared__ float red[1024];
    int tid = threadIdx.x;
    int j = blockIdx.x;
    int low = tid & 255;
    int b = ((j >> 5) << 3) + (low >> 5);
    int n = ((j & 31) << 5) + (low & 31);
    int kq = tid >> 8;

    const float* hrow = hprev + b * H_DIM + kq * 256;
    float acc = 0.f;
#pragma unroll 4
    for (int k = 0; k < 256; k += 8) {
        float4 h0 = *(const float4*)&hrow[k];
        float4 h1 = *(const float4*)&hrow[k + 4];
        int kk = kq * 256 + k;
        acc += h0.x * Wt[(kk + 0) * H_DIM + n] + h0.y * Wt[(kk + 1) * H_DIM + n]
             + h0.z * Wt[(kk + 2) * H_DIM + n] + h0.w * Wt[(kk + 3) * H_DIM + n]
             + h1.x * Wt[(kk + 4) * H_DIM + n] + h1.y * Wt[(kk + 5) * H_DIM + n]
             + h1.z * Wt[(kk + 6) * H_DIM + n] + h1.w * Wt[(kk + 7) * H_DIM + n];
    }
    red[tid] = acc;
    __syncthreads();
    if (tid < 256) {
        float s = red[tid] + red[tid + 256] + red[tid + 512] + red[tid + 768];
        int idx = (b * T_SEQ + t) * H_DIM + n;
        float h = tanhf(s + xW[idx]);
        hnext[b * H_DIM + n] = h;
        Hb[idx] = f2bf(h);
    }
}

// ---------------------------------------------------------------------------
// Kernel C: convert W_out fp32 -> bf16 copy (only if ws is big enough)
// ---------------------------------------------------------------------------
__global__ __launch_bounds__(256) void kconv(const float* __restrict__ W,
                                             uint16_t* __restrict__ Wb) {
    int i = (blockIdx.x * 256 + threadIdx.x) * 8;   // exactly covers 32,768,000
    float4 a = *(const float4*)&W[i];
    float4 c = *(const float4*)&W[i + 4];
    uint4 p;
    p.x = pack2(a.x, a.y); p.y = pack2(a.z, a.w);
    p.z = pack2(c.x, c.y); p.w = pack2(c.z, c.w);
    *(uint4*)&Wb[i] = p;
}

// ---------------------------------------------------------------------------
// Kernel G: out[m][v] = sum_k Hb[m][k] * Wout[v][k] + b_out[v]
// bf16 MFMA 16x16x32, 128x128 tile, BK=32, 4 waves (2x2), 4x4 frags/wave.
// Reg-staged LDS (conservative round-1 variant). Exact tiling: 4096=32*128,
// 32000=250*128, K=1024=32*32 -> no bounds checks.
// ---------------------------------------------------------------------------
template <bool BBF>
__global__ __launch_bounds__(256) void kgemm(const uint16_t* __restrict__ Ab,
                                             const void* __restrict__ Bp,
                                             const float* __restrict__ bout,
                                             float* __restrict__ out) {
    __shared__ __align__(16) uint16_t As[128 * 32];
    __shared__ __align__(16) uint16_t Bs[128 * 32];

    int bid = blockIdx.x;
    int mt = bid / 250, nt = bid % 250;   // consecutive bids share the A panel
    int m0 = mt * 128, n0 = nt * 128;
    int tid = threadIdx.x;
    int lane = tid & 63, wv = tid >> 6;
    int wm = wv >> 1, wn = wv & 1;

    const uint16_t* Bb = (const uint16_t*)Bp;
    const float*    Bf = (const float*)Bp;

    v4f acc[4][4] = {};

    int ar = lane & 15, ko = (lane >> 4) * 8;

    for (int k0 = 0; k0 < H_DIM; k0 += 32) {
        // ---- stage A (bf16 in ws) ----
#pragma unroll
        for (int l = 0; l < 2; ++l) {
            int c = tid + l * 256;            // 0..511
            int r = c >> 2, kof = (c & 3) * 8;
            uint4 v = *(const uint4*)&Ab[(m0 + r) * H_DIM + k0 + kof];
            *(uint4*)&As[r * 32 + kof] = v;
        }
        // ---- stage B ----
        if constexpr (BBF) {
#pragma unroll
            for (int l = 0; l < 2; ++l) {
                int c = tid + l * 256;
                int r = c >> 2, kof = (c & 3) * 8;
                uint4 v = *(const uint4*)&Bb[(n0 + r) * H_DIM + k0 + kof];
                *(uint4*)&Bs[r * 32 + kof] = v;
            }
        } else {
#pragma unroll
            for (int l = 0; l < 2; ++l) {
                int c = tid + l * 256;
                int r = c >> 2, kof = (c & 3) * 8;
                const float* src = &Bf[(n0 + r) * H_DIM + k0 + kof];
                float4 x = *(const float4*)src;
                float4 y = *(const float4*)(src + 4);
                uint4 p;
                p.x = pack2(x.x, x.y); p.y = pack2(x.z, x.w);
                p.z = pack2(y.x, y.y); p.w = pack2(y.z, y.w);
                *(uint4*)&Bs[r * 32 + kof] = p;
            }
        }
        __syncthreads();

        short8 a[4], bfr[4];
#pragma unroll
        for (int i = 0; i < 4; ++i)
            a[i] = *(const short8*)&As[(wm * 64 + i * 16 + ar) * 32 + ko];
#pragma unroll
        for (int jj = 0; jj < 4; ++jj)
            bfr[jj] = *(const short8*)&Bs[(wn * 64 + jj * 16 + ar) * 32 + ko];
#pragma unroll
        for (int i = 0; i < 4; ++i)
#pragma unroll
            for (int jj = 0; jj < 4; ++jj)
                acc[i][jj] = __builtin_amdgcn_mfma_f32_16x16x32_bf16(
                    a[i], bfr[jj], acc[i][jj], 0, 0, 0);
        __syncthreads();
    }

    // epilogue: D[row=(lane>>4)*4+q][col=lane&15], row<->A(m), col<->B(n)
    int fr = lane & 15, fq = lane >> 4;
#pragma unroll
    for (int jj = 0; jj < 4; ++jj) {
        int col = n0 + wn * 64 + jj * 16 + fr;
        float bo = bout[col];
#pragma unroll
        for (int i = 0; i < 4; ++i) {
            int row = m0 + wm * 64 + i * 16 + fq * 4;
#pragma unroll
            for (int q = 0; q < 4; ++q)
                out[(long)(row + q) * V_DIM + col] = acc[i][jj][q] + bo;
        }
    }
}

// ---------------------------------------------------------------------------
extern "C" void kernel_launch(void* const* d_in, const int* in_sizes, int n_in,
                              void* d_out, int out_size, void* d_ws, size_t ws_size,
                              hipStream_t stream) {
    const int*   target = (const int*)d_in[0];
    const float* h0     = (const float*)d_in[1];
    const float* emb    = (const float*)d_in[2];
    const float* Wih    = (const float*)d_in[3];
    const float* bih    = (const float*)d_in[4];
    const float* Whh    = (const float*)d_in[5];
    const float* bhh    = (const float*)d_in[6];
    const float* Wout   = (const float*)d_in[7];
    const float* bout   = (const float*)d_in[8];
    float* out = (float*)d_out;

    char* ws = (char*)d_ws;
    // ws layout (bytes):
    float*    xW   = (float*)(ws);                       // 16,777,216
    float*    Wt   = (float*)(ws + 16777216);            //  4,194,304
    float*    hbuf = (float*)(ws + 20971520);            //    262,144 (2x ping-pong)
    uint16_t* Hb   = (uint16_t*)(ws + 21233664);         //  8,388,608
    uint16_t* Wb   = (uint16_t*)(ws + 29622272);         // 65,536,000 (optional)
    const bool use_wb = ws_size >= 95158272ull;

    ktrans<<<dim3(32, 32), 256, 0, stream>>>(Whh, Wt);
    kxw<<<dim3(64, 16), 256, 0, stream>>>(target, emb, Wih, bih, bhh, xW);

    for (int t = 0; t < T_SEQ; ++t) {
        const float* hp = (t == 0) ? h0 : (hbuf + ((t + 1) & 1) * (B_SZ * H_DIM));
        float* hn = hbuf + (t & 1) * (B_SZ * H_DIM);
        kstep<<<128, 1024, 0, stream>>>(hp, Wt, xW, hn, Hb, t);
    }

    if (use_wb) {
        kconv<<<16000, 256, 0, stream>>>(Wout, Wb);
        kgemm<true><<<8000, 256, 0, stream>>>(Hb, (const void*)Wb, bout, out);
    } else {
        kgemm<false><<<8000, 256, 0, stream>>>(Hb, (const void*)Wout, bout, out);
    }
}